// Round 14
// baseline (3402.990 us; speedup 1.0000x reference)
//
#include <hip/hip_runtime.h>

typedef __attribute__((ext_vector_type(8))) short bf16x8;
typedef __attribute__((ext_vector_type(4))) float f32x4;
typedef unsigned short u16;

// ---------- helpers ----------
__device__ inline u16 f2b(float f) {
  union { float f; unsigned u; } x; x.f = f;
  unsigned r = x.u + 0x7FFFu + ((x.u >> 16) & 1u);
  return (u16)(r >> 16);
}
__device__ inline float b2f(u16 s) {
  union { unsigned u; float f; } x; x.u = ((unsigned)s) << 16;
  return x.f;
}
__device__ inline float gelu_f(float v) {
  return 0.5f * v * (1.0f + erff(v * 0.70710678118654752f));
}
__device__ inline void gll16(const void* g, void* lds) {
  __builtin_amdgcn_global_load_lds((const __attribute__((address_space(1))) void*)g,
                                   (__attribute__((address_space(3))) void*)lds,
                                   16, 0, 0);
}

// ---------- weight convert fp32 -> bf16 ----------
__global__ __launch_bounds__(256) void cvt_w(const float* __restrict__ s,
                                             u16* __restrict__ d, int n4) {
  int i = blockIdx.x * 256 + threadIdx.x;
  if (i < n4) {
    float4 v = ((const float4*)s)[i];
    ushort4 o; o.x = f2b(v.x); o.y = f2b(v.y); o.z = f2b(v.z); o.w = f2b(v.w);
    ((ushort4*)d)[i] = o;
  }
}

__global__ __launch_bounds__(256) void cat_bias(const float* __restrict__ a,
                                                const float* __restrict__ b,
                                                float* __restrict__ o,
                                                float* __restrict__ z) {
  int i = blockIdx.x * 256 + threadIdx.x;
  if (i < 1024) { o[i] = a[i]; o[1024 + i] = b[i]; z[i] = 0.f; }
}

// ---------- fused x->bf16 convert + 2x2x2 mean pool ----------
__global__ __launch_bounds__(256) void pool_cvt(const float* __restrict__ xg,
                                                u16* __restrict__ Xb,
                                                u16* __restrict__ Qp) {
  int qr = blockIdx.x;
  int wgi = qr & 15;
  int hgi = (qr >> 4) % 20;
  int dgi = qr / 320;
  int c = threadIdx.x * 4;
  float sx = 0.f, sy = 0.f, sz = 0.f, sw = 0.f;
#pragma unroll
  for (int j = 0; j < 8; ++j) {
    int tr = ((2 * dgi + (j >> 2)) * 40 + (2 * hgi + ((j >> 1) & 1))) * 32 +
             (2 * wgi + (j & 1));
    long off = (long)tr * 1024 + c;
    float4 v = *(const float4*)&xg[off];
    ushort4 o; o.x = f2b(v.x); o.y = f2b(v.y); o.z = f2b(v.z); o.w = f2b(v.w);
    *(ushort4*)&Xb[off] = o;
    sx += v.x; sy += v.y; sz += v.z; sw += v.w;
  }
  ushort4 o;
  o.x = f2b(sx * 0.125f); o.y = f2b(sy * 0.125f);
  o.z = f2b(sz * 0.125f); o.w = f2b(sw * 0.125f);
  *(ushort4*)&Qp[(long)qr * 1024 + c] = o;
}

// ---------- fused triple-buffer LayerNorm (K, V, Q in one dispatch) --------
__global__ __launch_bounds__(256) void ln3_ip(u16* X1, const float* w1,
                                              const float* b1, u16* X2,
                                              const float* w2, const float* b2,
                                              u16* X3, const float* w3,
                                              const float* b3, long rows1,
                                              long rows2) {
  long row = blockIdx.x;
  u16* X = X1; const float* w = w1; const float* b = b1;
  if (row >= rows1 + rows2) { X = X3; w = w3; b = b3; row -= rows1 + rows2; }
  else if (row >= rows1)    { X = X2; w = w2; b = b2; row -= rows1; }
  int c = threadIdx.x * 4;
  ushort4 v = *(const ushort4*)&X[row * 1024 + c];
  float f0 = b2f(v.x), f1 = b2f(v.y), f2 = b2f(v.z), f3 = b2f(v.w);
  float s = f0 + f1 + f2 + f3;
  float q = f0 * f0 + f1 * f1 + f2 * f2 + f3 * f3;
#pragma unroll
  for (int off = 32; off >= 1; off >>= 1) {
    s += __shfl_xor(s, off);
    q += __shfl_xor(q, off);
  }
  __shared__ float red[8];
  int wv = threadIdx.x >> 6, ln = threadIdx.x & 63;
  if (ln == 0) { red[wv] = s; red[4 + wv] = q; }
  __syncthreads();
  s = red[0] + red[1] + red[2] + red[3];
  q = red[4] + red[5] + red[6] + red[7];
  float mean = s * (1.f / 1024.f);
  float var = q * (1.f / 1024.f) - mean * mean;
  float rs = rsqrtf(var + 1e-6f);
  float4 wv4 = *(const float4*)&w[c];
  float4 bv4 = *(const float4*)&b[c];
  ushort4 o;
  o.x = f2b((f0 - mean) * rs * wv4.x + bv4.x);
  o.y = f2b((f1 - mean) * rs * wv4.y + bv4.y);
  o.z = f2b((f2 - mean) * rs * wv4.z + bv4.z);
  o.w = f2b((f3 - mean) * rs * wv4.w + bv4.w);
  *(ushort4*)&X[row * 1024 + c] = o;
}

#define MFMA16(a, b, c) __builtin_amdgcn_mfma_f32_16x16x32_bf16((a), (b), (c), 0, 0, 0)

// ---------- 128x128 2-phase GEMM (R11/R13 verified) + 3-way group ----------
// C[M,N] = A[M,K(lda)] @ B[N,K]^T (+bias, epilogue)
// EPI: 0 bias->bf16 ; 1 bias+gelu->bf16 ; 2 bias->fp32 ; 3 nobias->bf16
// KT = compile-time K (full unroll; staging addrs fold into gll16 imm).
// __launch_bounds__(256,5): VGPR 60 <= 102 budget; 5 x 32KB LDS = 160KB
// (full CU pool) -> 5 blocks/CU, 20 waves (R11 mechanism, one step further).
#define BK 32
template <int EPI, int KT>
__global__ __launch_bounds__(256, 5) void gemm_bt(const u16* A, const u16* B,
                                                  const float* bias,
                                                  float* __restrict__ Cf, u16* Cb,
                                                  int M1, int N, int lda,
                                                  int nbx, int nby,
                                                  const u16* A2, const u16* B2,
                                                  const float* bias2, u16* Cb2,
                                                  int M2, int lda2,
                                                  const u16* A3, const u16* B3,
                                                  const float* bias3, u16* Cb3,
                                                  int M3, int lda3) {
  __shared__ __align__(16) u16 As0[128 * BK];
  __shared__ __align__(16) u16 Bs0[128 * BK];
  __shared__ __align__(16) u16 As1[128 * BK];
  __shared__ __align__(16) u16 Bs1[128 * BK];
  const int tid = threadIdx.x;

  int L = blockIdx.x, bx, by;
  if ((nbx & 7) == 0) {
    int xcd = L & 7, j = L >> 3, ppx = nbx >> 3;
    int pj = j / nby;
    bx = xcd * ppx + pj;
    by = j - pj * nby;
  } else {
    bx = L % nbx;
    by = L / nbx;
  }
  int bm = bx * 128;
  const int bn = by * 128;

  int M = M1;
  if (bm >= M1) {
    if (bm < M1 + M2) { A = A2; B = B2; bias = bias2; Cb = Cb2; bm -= M1; M = M2; lda = lda2; }
    else { A = A3; B = B3; bias = bias3; Cb = Cb3; bm -= (M1 + M2); M = M3; lda = lda3; }
  }

  const int l = tid & 63, wv = tid >> 6;
  const int wm = (wv >> 1) * 64, wn = (wv & 1) * 64;
  const int lr = l & 15, kg = l >> 4;

  // staging: chunk q in {tid, 256+tid}; row r=q>>2; swizzled source col-chunk
  const int q0 = tid, q1 = 256 + tid;
  const int r0 = q0 >> 2, r1 = q1 >> 2;
  const int ca = ((q0 & 3) ^ ((r0 >> 1) & 3)) * 8;
  const int cbn = ((q1 & 3) ^ ((r1 >> 1) & 3)) * 8;
  const int ea = q0 * 8, eb = q1 * 8;  // linear LDS dests
  int gra = bm + r0; if (gra > M - 1) gra = M - 1;
  int grb = bm + r1; if (grb > M - 1) grb = M - 1;
  const u16* pa0 = A + (long)gra * lda + ca;
  const u16* pa1 = A + (long)grb * lda + cbn;
  const u16* pb0 = B + (long)(bn + r0) * KT + ca;
  const u16* pb1 = B + (long)(bn + r1) * KT + cbn;

  // conflict-free swizzled read chunk offset (verified R10: conflicts = 0)
  const int swz = (kg ^ ((lr >> 1) & 3)) * 8;

  f32x4 acc[4][4] = {};
  const int nt = KT / BK;

#define STAGE(AS, BS, k0)                \
  do {                                   \
    gll16(pa0 + (k0), &(AS)[ea]);        \
    gll16(pb0 + (k0), &(BS)[ea]);        \
    gll16(pa1 + (k0), &(AS)[eb]);        \
    gll16(pb1 + (k0), &(BS)[eb]);        \
  } while (0)

#define COMPUTE(AS, BS)                                                       \
  do {                                                                        \
    bf16x8 af[4], bfr[4];                                                     \
    _Pragma("unroll") for (int m = 0; m < 4; ++m)                             \
        af[m] = *(const bf16x8*)&(AS)[(wm + m * 16 + lr) * BK + swz];         \
    _Pragma("unroll") for (int n = 0; n < 4; ++n)                             \
        bfr[n] = *(const bf16x8*)&(BS)[(wn + n * 16 + lr) * BK + swz];        \
    _Pragma("unroll") for (int m = 0; m < 4; ++m)                             \
        _Pragma("unroll") for (int n = 0; n < 4; ++n)                         \
            acc[m][n] = MFMA16(af[m], bfr[n], acc[m][n]);                     \
  } while (0)

  STAGE(As0, Bs0, 0);
  __syncthreads();
#pragma unroll
  for (int t = 0; t < nt; t += 2) {
    if (t + 1 < nt) STAGE(As1, Bs1, (t + 1) * BK);
    COMPUTE(As0, Bs0);
    __syncthreads();
    if (t + 2 < nt) STAGE(As0, Bs0, (t + 2) * BK);
    COMPUTE(As1, Bs1);
    __syncthreads();
  }
#undef STAGE
#undef COMPUTE

#pragma unroll
  for (int m = 0; m < 4; ++m) {
    int row0 = bm + wm + m * 16 + kg * 4;
#pragma unroll
    for (int n = 0; n < 4; ++n) {
      int col = bn + wn + n * 16 + lr;
      float bsv = (EPI == 3) ? 0.f : bias[col];
#pragma unroll
      for (int r = 0; r < 4; ++r) {
        int row = row0 + r;
        if (row < M) {
          float v = acc[m][n][r] + bsv;
          if (EPI == 1) v = gelu_f(v);
          if (EPI == 2) Cf[(long)row * N + col] = v;
          else Cb[(long)row * N + col] = f2b(v);
        }
      }
    }
  }
}

// ---------- 8-key local attention ----------
__global__ __launch_bounds__(256) void attn_k(const u16* __restrict__ QH,
                                              const u16* __restrict__ KH,
                                              const u16* __restrict__ VH,
                                              u16* __restrict__ O) {
  int qr = blockIdx.x;
  int wgi = qr & 15;
  int hgi = (qr >> 4) % 20;
  int dgi = qr / 320;
  int c0 = (threadIdx.x >> 5) * 128 + (threadIdx.x & 31) * 4;
  ushort4 qv = *(const ushort4*)&QH[(long)qr * 1024 + c0];
  float q0 = b2f(qv.x), q1 = b2f(qv.y), q2 = b2f(qv.z), q3 = b2f(qv.w);
  long trs[8];
  float sc[8];
#pragma unroll
  for (int j = 0; j < 8; ++j) {
    int tr = ((2 * dgi + (j >> 2)) * 40 + (2 * hgi + ((j >> 1) & 1))) * 32 +
             (2 * wgi + (j & 1));
    trs[j] = (long)tr * 1024 + c0;
    ushort4 kv = *(const ushort4*)&KH[trs[j]];
    float p = q0 * b2f(kv.x) + q1 * b2f(kv.y) + q2 * b2f(kv.z) + q3 * b2f(kv.w);
    p += __shfl_xor(p, 16); p += __shfl_xor(p, 8); p += __shfl_xor(p, 4);
    p += __shfl_xor(p, 2);  p += __shfl_xor(p, 1);
    sc[j] = p * 0.088388347648318447f;  // 1/sqrt(128)
  }
  float mx = sc[0];
#pragma unroll
  for (int j = 1; j < 8; ++j) mx = fmaxf(mx, sc[j]);
  float ssum = 0.f;
#pragma unroll
  for (int j = 0; j < 8; ++j) { sc[j] = expf(sc[j] - mx); ssum += sc[j]; }
  float inv = 1.0f / ssum;
  float o0 = 0, o1 = 0, o2 = 0, o3 = 0;
#pragma unroll
  for (int j = 0; j < 8; ++j) {
    ushort4 vv = *(const ushort4*)&VH[trs[j]];
    float p = sc[j] * inv;
    o0 += p * b2f(vv.x); o1 += p * b2f(vv.y);
    o2 += p * b2f(vv.z); o3 += p * b2f(vv.w);
  }
  ushort4 ov; ov.x = f2b(o0); ov.y = f2b(o1); ov.z = f2b(o2); ov.w = f2b(o3);
  *(ushort4*)&O[(long)qr * 1024 + c0] = ov;
}

// ---------- host ----------
extern "C" void kernel_launch(void* const* d_in, const int* in_sizes, int n_in,
                              void* d_out, int out_size, void* d_ws,
                              size_t ws_size, hipStream_t stream) {
  const float* x      = (const float*)d_in[0];
  const float* q_w    = (const float*)d_in[1];
  const float* k_w1   = (const float*)d_in[2];
  const float* k_b1   = (const float*)d_in[3];
  const float* k_w2   = (const float*)d_in[4];
  const float* k_b2   = (const float*)d_in[5];
  const float* v_w1   = (const float*)d_in[6];
  const float* v_b1   = (const float*)d_in[7];
  const float* v_w2   = (const float*)d_in[8];
  const float* v_b2   = (const float*)d_in[9];
  const float* lnq_w  = (const float*)d_in[10];
  const float* lnq_b  = (const float*)d_in[11];
  const float* lnk_w  = (const float*)d_in[12];
  const float* lnk_b  = (const float*)d_in[13];
  const float* lnv_w  = (const float*)d_in[14];
  const float* lnv_b  = (const float*)d_in[15];
  const float* in_w   = (const float*)d_in[16];
  const float* in_b   = (const float*)d_in[17];
  const float* out_w  = (const float*)d_in[18];
  const float* out_b  = (const float*)d_in[19];
  const float* mlp_w1 = (const float*)d_in[20];
  const float* mlp_b1 = (const float*)d_in[21];
  const float* mlp_w2 = (const float*)d_in[22];
  const float* mlp_b2 = (const float*)d_in[23];
  float* out = (float*)d_out;

  char* base = (char*)d_ws;
  size_t off = 0;
  auto alloc_us = [&](size_t elems) -> u16* {
    u16* r = (u16*)(base + off);
    off += ((elems * 2 + 255) & ~(size_t)255);
    return r;
  };
  const size_t CC = 1024 * 1024;
  u16* wb_q   = alloc_us(CC);
  u16* wb_kv1 = alloc_us(2 * CC);
  u16* wb_k2  = alloc_us(CC);
  u16* wb_v2  = alloc_us(CC);
  u16* wb_in  = alloc_us(3 * CC);
  u16* wb_out = alloc_us(CC);
  u16* wb_m1  = alloc_us(2 * CC);
  u16* wb_m2  = alloc_us(4 * CC);
  float* b_kv1 = (float*)(base + off); off += 2048 * 4;
  float* b_zero = (float*)(base + off); off += 1024 * 4;

  auto cvt = [&](const float* s, u16* d, size_t n) {
    int n4 = (int)(n / 4);
    cvt_w<<<(n4 + 255) / 256, 256, 0, stream>>>(s, d, n4);
  };
  cvt(q_w, wb_q, CC);
  cvt(k_w1, wb_kv1, CC);        cvt(v_w1, wb_kv1 + CC, CC);
  cvt(k_w2, wb_k2, CC);         cvt(v_w2, wb_v2, CC);
  cvt(in_w, wb_in, 3 * CC);     cvt(out_w, wb_out, CC);
  cvt(mlp_w1, wb_m1, 2 * CC);   cvt(mlp_w2, wb_m2, 4 * CC);
  cat_bias<<<4, 256, 0, stream>>>(k_b1, v_b1, b_kv1, b_zero);

  // Flat token space: 32 dg-planes of 2560 tokens; largest chunk that fits.
  int dgc = 1;
  for (int cand = 32; cand >= 1; cand >>= 1) {
    size_t Tc_ = (size_t)cand * 2560;
    if (off + Tc_ * 11520ull + (1ull << 20) <= ws_size) { dgc = cand; break; }
  }
  const int Tc = dgc * 2560;   // tokens per chunk
  const int Tq = dgc * 320;    // queries per chunk

  u16* Xb  = alloc_us((size_t)Tc * 1024);
  u16* Hb2 = alloc_us((size_t)Tc * 2048);
  u16* Kb  = alloc_us((size_t)Tc * 1024);
  u16* Vb  = alloc_us((size_t)Tc * 1024);
  u16* Qp  = alloc_us((size_t)Tq * 1024);
  u16* QQ  = alloc_us((size_t)Tq * 1024);
  u16* QHb = alloc_us((size_t)Tq * 1024);
  u16* Ob  = alloc_us((size_t)Tq * 1024);
  u16* O2  = alloc_us((size_t)Tq * 1024);
  u16* Hm  = Kb;  // final-MLP hidden reuses Kb (Tq*2048 <= Tc*1024)

  auto launch = [&](int EPI, int N, int K,
                    const u16* A1, const u16* B1, const float* s1, u16* C1,
                    int M1, int lda1,
                    const u16* A2, const u16* B2, const float* s2, u16* C2,
                    int M2, int lda2,
                    const u16* A3, const u16* B3, const float* s3, u16* C3,
                    int M3, int lda3, float* Cf) {
    int nbx = (M1 + M2 + M3) / 128, nby = N / 128;
    dim3 g(nbx * nby);
    if (K == 1024) {
      switch (EPI) {
        case 0: gemm_bt<0, 1024><<<g, 256, 0, stream>>>(A1, B1, s1, Cf, C1, M1, N, lda1, nbx, nby, A2, B2, s2, C2, M2, lda2, A3, B3, s3, C3, M3, lda3); break;
        case 1: gemm_bt<1, 1024><<<g, 256, 0, stream>>>(A1, B1, s1, Cf, C1, M1, N, lda1, nbx, nby, A2, B2, s2, C2, M2, lda2, A3, B3, s3, C3, M3, lda3); break;
        case 2: gemm_bt<2, 1024><<<g, 256, 0, stream>>>(A1, B1, s1, Cf, C1, M1, N, lda1, nbx, nby, A2, B2, s2, C2, M2, lda2, A3, B3, s3, C3, M3, lda3); break;
        default: gemm_bt<3, 1024><<<g, 256, 0, stream>>>(A1, B1, s1, Cf, C1, M1, N, lda1, nbx, nby, A2, B2, s2, C2, M2, lda2, A3, B3, s3, C3, M3, lda3); break;
      }
    } else {
      switch (EPI) {
        case 0: gemm_bt<0, 2048><<<g, 256, 0, stream>>>(A1, B1, s1, Cf, C1, M1, N, lda1, nbx, nby, A2, B2, s2, C2, M2, lda2, A3, B3, s3, C3, M3, lda3); break;
        case 1: gemm_bt<1, 2048><<<g, 256, 0, stream>>>(A1, B1, s1, Cf, C1, M1, N, lda1, nbx, nby, A2, B2, s2, C2, M2, lda2, A3, B3, s3, C3, M3, lda3); break;
        case 2: gemm_bt<2, 2048><<<g, 256, 0, stream>>>(A1, B1, s1, Cf, C1, M1, N, lda1, nbx, nby, A2, B2, s2, C2, M2, lda2, A3, B3, s3, C3, M3, lda3); break;
        default: gemm_bt<3, 2048><<<g, 256, 0, stream>>>(A1, B1, s1, Cf, C1, M1, N, lda1, nbx, nby, A2, B2, s2, C2, M2, lda2, A3, B3, s3, C3, M3, lda3); break;
      }
    }
  };
  const u16* Z = nullptr;

  for (int dg0 = 0; dg0 < 32; dg0 += dgc) {
    const float* xg = x + (size_t)dg0 * 2560 * 1024;
    long q0g = (long)dg0 * 320;

    pool_cvt<<<Tq, 256, 0, stream>>>(xg, Xb, Qp);

    // fused k1+v1 -> gelu -> Hb2 (Tc x 2048)
    launch(1, 2048, 1024, Xb, wb_kv1, b_kv1, Hb2, Tc, 1024,
           Z, Z, nullptr, nullptr, 0, 0, Z, Z, nullptr, nullptr, 0, 0, nullptr);

    // grouped k2 + v2 + q-proj (N=1024, K=1024; per-group lda)
    launch(0, 1024, 1024, Hb2, wb_k2, k_b2, Kb, Tc, 2048,
           Hb2 + 1024, wb_v2, v_b2, Vb, Tc, 2048,
           Qp, wb_q, b_zero, QQ, Tq, 1024, nullptr);

    // fused LN(K) + LN(V) + LN(Q)
    ln3_ip<<<2 * Tc + Tq, 256, 0, stream>>>(Kb, lnk_w, lnk_b, Vb, lnv_w, lnv_b,
                                            QQ, lnq_w, lnq_b, Tc, Tc);

    // grouped kh + vh + qh (all N=1024, K=1024, lda=1024)
    launch(0, 1024, 1024, Kb, wb_in + CC, in_b + 1024, Xb, Tc, 1024,
           Vb, wb_in + 2 * CC, in_b + 2048, Hb2, Tc, 1024,
           QQ, wb_in, in_b, QHb, Tq, 1024, nullptr);

    attn_k<<<Tq, 256, 0, stream>>>(QHb, Xb, Hb2, Ob);

    // out-proj, then final MLP
    launch(0, 1024, 1024, Ob, wb_out, out_b, O2, Tq, 1024,
           Z, Z, nullptr, nullptr, 0, 0, Z, Z, nullptr, nullptr, 0, 0, nullptr);
    launch(1, 2048, 1024, O2, wb_m1, mlp_b1, Hm, Tq, 1024,
           Z, Z, nullptr, nullptr, 0, 0, Z, Z, nullptr, nullptr, 0, 0, nullptr);
    launch(2, 2048, 2048, Hm, wb_m2, mlp_b2, nullptr, Tq, 2048,
           Z, Z, nullptr, nullptr, 0, 0, Z, Z, nullptr, nullptr, 0, 0,
           out + q0g * 2048);
  }
}

// Round 15
// 2203.478 us; speedup vs baseline: 1.5444x; 1.5444x over previous
//
#include <hip/hip_runtime.h>

typedef __attribute__((ext_vector_type(8))) short bf16x8;
typedef __attribute__((ext_vector_type(4))) float f32x4;
typedef unsigned short u16;

// ---------- helpers ----------
__device__ inline u16 f2b(float f) {
  union { float f; unsigned u; } x; x.f = f;
  unsigned r = x.u + 0x7FFFu + ((x.u >> 16) & 1u);
  return (u16)(r >> 16);
}
__device__ inline float b2f(u16 s) {
  union { unsigned u; float f; } x; x.u = ((unsigned)s) << 16;
  return x.f;
}
__device__ inline float gelu_f(float v) {
  return 0.5f * v * (1.0f + erff(v * 0.70710678118654752f));
}
__device__ inline void gll16(const void* g, void* lds) {
  __builtin_amdgcn_global_load_lds((const __attribute__((address_space(1))) void*)g,
                                   (__attribute__((address_space(3))) void*)lds,
                                   16, 0, 0);
}

// ---------- weight convert fp32 -> bf16 ----------
__global__ __launch_bounds__(256) void cvt_w(const float* __restrict__ s,
                                             u16* __restrict__ d, int n4) {
  int i = blockIdx.x * 256 + threadIdx.x;
  if (i < n4) {
    float4 v = ((const float4*)s)[i];
    ushort4 o; o.x = f2b(v.x); o.y = f2b(v.y); o.z = f2b(v.z); o.w = f2b(v.w);
    ((ushort4*)d)[i] = o;
  }
}

__global__ __launch_bounds__(256) void cat_bias(const float* __restrict__ a,
                                                const float* __restrict__ b,
                                                float* __restrict__ o,
                                                float* __restrict__ z) {
  int i = blockIdx.x * 256 + threadIdx.x;
  if (i < 1024) { o[i] = a[i]; o[1024 + i] = b[i]; z[i] = 0.f; }
}

// ---------- fused x->bf16 convert + 2x2x2 mean pool ----------
__global__ __launch_bounds__(256) void pool_cvt(const float* __restrict__ xg,
                                                u16* __restrict__ Xb,
                                                u16* __restrict__ Qp) {
  int qr = blockIdx.x;
  int wgi = qr & 15;
  int hgi = (qr >> 4) % 20;
  int dgi = qr / 320;
  int c = threadIdx.x * 4;
  float sx = 0.f, sy = 0.f, sz = 0.f, sw = 0.f;
#pragma unroll
  for (int j = 0; j < 8; ++j) {
    int tr = ((2 * dgi + (j >> 2)) * 40 + (2 * hgi + ((j >> 1) & 1))) * 32 +
             (2 * wgi + (j & 1));
    long off = (long)tr * 1024 + c;
    float4 v = *(const float4*)&xg[off];
    ushort4 o; o.x = f2b(v.x); o.y = f2b(v.y); o.z = f2b(v.z); o.w = f2b(v.w);
    *(ushort4*)&Xb[off] = o;
    sx += v.x; sy += v.y; sz += v.z; sw += v.w;
  }
  ushort4 o;
  o.x = f2b(sx * 0.125f); o.y = f2b(sy * 0.125f);
  o.z = f2b(sz * 0.125f); o.w = f2b(sw * 0.125f);
  *(ushort4*)&Qp[(long)qr * 1024 + c] = o;
}

// ---------- fused triple-buffer LayerNorm (K, V, Q in one dispatch) --------
__global__ __launch_bounds__(256) void ln3_ip(u16* X1, const float* w1,
                                              const float* b1, u16* X2,
                                              const float* w2, const float* b2,
                                              u16* X3, const float* w3,
                                              const float* b3, long rows1,
                                              long rows2) {
  long row = blockIdx.x;
  u16* X = X1; const float* w = w1; const float* b = b1;
  if (row >= rows1 + rows2) { X = X3; w = w3; b = b3; row -= rows1 + rows2; }
  else if (row >= rows1)    { X = X2; w = w2; b = b2; row -= rows1; }
  int c = threadIdx.x * 4;
  ushort4 v = *(const ushort4*)&X[row * 1024 + c];
  float f0 = b2f(v.x), f1 = b2f(v.y), f2 = b2f(v.z), f3 = b2f(v.w);
  float s = f0 + f1 + f2 + f3;
  float q = f0 * f0 + f1 * f1 + f2 * f2 + f3 * f3;
#pragma unroll
  for (int off = 32; off >= 1; off >>= 1) {
    s += __shfl_xor(s, off);
    q += __shfl_xor(q, off);
  }
  __shared__ float red[8];
  int wv = threadIdx.x >> 6, ln = threadIdx.x & 63;
  if (ln == 0) { red[wv] = s; red[4 + wv] = q; }
  __syncthreads();
  s = red[0] + red[1] + red[2] + red[3];
  q = red[4] + red[5] + red[6] + red[7];
  float mean = s * (1.f / 1024.f);
  float var = q * (1.f / 1024.f) - mean * mean;
  float rs = rsqrtf(var + 1e-6f);
  float4 wv4 = *(const float4*)&w[c];
  float4 bv4 = *(const float4*)&b[c];
  ushort4 o;
  o.x = f2b((f0 - mean) * rs * wv4.x + bv4.x);
  o.y = f2b((f1 - mean) * rs * wv4.y + bv4.y);
  o.z = f2b((f2 - mean) * rs * wv4.z + bv4.z);
  o.w = f2b((f3 - mean) * rs * wv4.w + bv4.w);
  *(ushort4*)&X[row * 1024 + c] = o;
}

#define MFMA16(a, b, c) __builtin_amdgcn_mfma_f32_16x16x32_bf16((a), (b), (c), 0, 0, 0)

// ---------- 128x128 2-phase GEMM (R13 verified best) + 3-way group ---------
// C[M,N] = A[M,K(lda)] @ B[N,K]^T (+bias, epilogue)
// EPI: 0 bias->bf16 ; 1 bias+gelu->bf16 ; 2 bias->fp32 ; 3 nobias->bf16
// KT = compile-time K (full unroll; staging addrs fold into gll16 imm).
// __launch_bounds__(256,4): 60 VGPR, 4 blocks/CU, Occ 45% — the verified
// optimum. (5 blocks/CU spills acc -> scratch: R14, 990us/dispatch.)
#define BK 32
template <int EPI, int KT>
__global__ __launch_bounds__(256, 4) void gemm_bt(const u16* A, const u16* B,
                                                  const float* bias,
                                                  float* __restrict__ Cf, u16* Cb,
                                                  int M1, int N, int lda,
                                                  int nbx, int nby,
                                                  const u16* A2, const u16* B2,
                                                  const float* bias2, u16* Cb2,
                                                  int M2, int lda2,
                                                  const u16* A3, const u16* B3,
                                                  const float* bias3, u16* Cb3,
                                                  int M3, int lda3) {
  __shared__ __align__(16) u16 As0[128 * BK];
  __shared__ __align__(16) u16 Bs0[128 * BK];
  __shared__ __align__(16) u16 As1[128 * BK];
  __shared__ __align__(16) u16 Bs1[128 * BK];
  const int tid = threadIdx.x;

  int L = blockIdx.x, bx, by;
  if ((nbx & 7) == 0) {
    int xcd = L & 7, j = L >> 3, ppx = nbx >> 3;
    int pj = j / nby;
    bx = xcd * ppx + pj;
    by = j - pj * nby;
  } else {
    bx = L % nbx;
    by = L / nbx;
  }
  int bm = bx * 128;
  const int bn = by * 128;

  int M = M1;
  if (bm >= M1) {
    if (bm < M1 + M2) { A = A2; B = B2; bias = bias2; Cb = Cb2; bm -= M1; M = M2; lda = lda2; }
    else { A = A3; B = B3; bias = bias3; Cb = Cb3; bm -= (M1 + M2); M = M3; lda = lda3; }
  }

  const int l = tid & 63, wv = tid >> 6;
  const int wm = (wv >> 1) * 64, wn = (wv & 1) * 64;
  const int lr = l & 15, kg = l >> 4;

  // staging: chunk q in {tid, 256+tid}; row r=q>>2; swizzled source col-chunk
  const int q0 = tid, q1 = 256 + tid;
  const int r0 = q0 >> 2, r1 = q1 >> 2;
  const int ca = ((q0 & 3) ^ ((r0 >> 1) & 3)) * 8;
  const int cbn = ((q1 & 3) ^ ((r1 >> 1) & 3)) * 8;
  const int ea = q0 * 8, eb = q1 * 8;  // linear LDS dests
  int gra = bm + r0; if (gra > M - 1) gra = M - 1;
  int grb = bm + r1; if (grb > M - 1) grb = M - 1;
  const u16* pa0 = A + (long)gra * lda + ca;
  const u16* pa1 = A + (long)grb * lda + cbn;
  const u16* pb0 = B + (long)(bn + r0) * KT + ca;
  const u16* pb1 = B + (long)(bn + r1) * KT + cbn;

  // conflict-free swizzled read chunk offset (verified R10: conflicts = 0)
  const int swz = (kg ^ ((lr >> 1) & 3)) * 8;

  f32x4 acc[4][4] = {};
  const int nt = KT / BK;

#define STAGE(AS, BS, k0)                \
  do {                                   \
    gll16(pa0 + (k0), &(AS)[ea]);        \
    gll16(pb0 + (k0), &(BS)[ea]);        \
    gll16(pa1 + (k0), &(AS)[eb]);        \
    gll16(pb1 + (k0), &(BS)[eb]);        \
  } while (0)

#define COMPUTE(AS, BS)                                                       \
  do {                                                                        \
    bf16x8 af[4], bfr[4];                                                     \
    _Pragma("unroll") for (int m = 0; m < 4; ++m)                             \
        af[m] = *(const bf16x8*)&(AS)[(wm + m * 16 + lr) * BK + swz];         \
    _Pragma("unroll") for (int n = 0; n < 4; ++n)                             \
        bfr[n] = *(const bf16x8*)&(BS)[(wn + n * 16 + lr) * BK + swz];        \
    _Pragma("unroll") for (int m = 0; m < 4; ++m)                             \
        _Pragma("unroll") for (int n = 0; n < 4; ++n)                         \
            acc[m][n] = MFMA16(af[m], bfr[n], acc[m][n]);                     \
  } while (0)

  STAGE(As0, Bs0, 0);
  __syncthreads();
#pragma unroll
  for (int t = 0; t < nt; t += 2) {
    if (t + 1 < nt) STAGE(As1, Bs1, (t + 1) * BK);
    COMPUTE(As0, Bs0);
    __syncthreads();
    if (t + 2 < nt) STAGE(As0, Bs0, (t + 2) * BK);
    COMPUTE(As1, Bs1);
    __syncthreads();
  }
#undef STAGE
#undef COMPUTE

#pragma unroll
  for (int m = 0; m < 4; ++m) {
    int row0 = bm + wm + m * 16 + kg * 4;
#pragma unroll
    for (int n = 0; n < 4; ++n) {
      int col = bn + wn + n * 16 + lr;
      float bsv = (EPI == 3) ? 0.f : bias[col];
#pragma unroll
      for (int r = 0; r < 4; ++r) {
        int row = row0 + r;
        if (row < M) {
          float v = acc[m][n][r] + bsv;
          if (EPI == 1) v = gelu_f(v);
          if (EPI == 2) Cf[(long)row * N + col] = v;
          else Cb[(long)row * N + col] = f2b(v);
        }
      }
    }
  }
}

// ---------- 8-key local attention ----------
__global__ __launch_bounds__(256) void attn_k(const u16* __restrict__ QH,
                                              const u16* __restrict__ KH,
                                              const u16* __restrict__ VH,
                                              u16* __restrict__ O) {
  int qr = blockIdx.x;
  int wgi = qr & 15;
  int hgi = (qr >> 4) % 20;
  int dgi = qr / 320;
  int c0 = (threadIdx.x >> 5) * 128 + (threadIdx.x & 31) * 4;
  ushort4 qv = *(const ushort4*)&QH[(long)qr * 1024 + c0];
  float q0 = b2f(qv.x), q1 = b2f(qv.y), q2 = b2f(qv.z), q3 = b2f(qv.w);
  long trs[8];
  float sc[8];
#pragma unroll
  for (int j = 0; j < 8; ++j) {
    int tr = ((2 * dgi + (j >> 2)) * 40 + (2 * hgi + ((j >> 1) & 1))) * 32 +
             (2 * wgi + (j & 1));
    trs[j] = (long)tr * 1024 + c0;
    ushort4 kv = *(const ushort4*)&KH[trs[j]];
    float p = q0 * b2f(kv.x) + q1 * b2f(kv.y) + q2 * b2f(kv.z) + q3 * b2f(kv.w);
    p += __shfl_xor(p, 16); p += __shfl_xor(p, 8); p += __shfl_xor(p, 4);
    p += __shfl_xor(p, 2);  p += __shfl_xor(p, 1);
    sc[j] = p * 0.088388347648318447f;  // 1/sqrt(128)
  }
  float mx = sc[0];
#pragma unroll
  for (int j = 1; j < 8; ++j) mx = fmaxf(mx, sc[j]);
  float ssum = 0.f;
#pragma unroll
  for (int j = 0; j < 8; ++j) { sc[j] = expf(sc[j] - mx); ssum += sc[j]; }
  float inv = 1.0f / ssum;
  float o0 = 0, o1 = 0, o2 = 0, o3 = 0;
#pragma unroll
  for (int j = 0; j < 8; ++j) {
    ushort4 vv = *(const ushort4*)&VH[trs[j]];
    float p = sc[j] * inv;
    o0 += p * b2f(vv.x); o1 += p * b2f(vv.y);
    o2 += p * b2f(vv.z); o3 += p * b2f(vv.w);
  }
  ushort4 ov; ov.x = f2b(o0); ov.y = f2b(o1); ov.z = f2b(o2); ov.w = f2b(o3);
  *(ushort4*)&O[(long)qr * 1024 + c0] = ov;
}

// ---------- host ----------
extern "C" void kernel_launch(void* const* d_in, const int* in_sizes, int n_in,
                              void* d_out, int out_size, void* d_ws,
                              size_t ws_size, hipStream_t stream) {
  const float* x      = (const float*)d_in[0];
  const float* q_w    = (const float*)d_in[1];
  const float* k_w1   = (const float*)d_in[2];
  const float* k_b1   = (const float*)d_in[3];
  const float* k_w2   = (const float*)d_in[4];
  const float* k_b2   = (const float*)d_in[5];
  const float* v_w1   = (const float*)d_in[6];
  const float* v_b1   = (const float*)d_in[7];
  const float* v_w2   = (const float*)d_in[8];
  const float* v_b2   = (const float*)d_in[9];
  const float* lnq_w  = (const float*)d_in[10];
  const float* lnq_b  = (const float*)d_in[11];
  const float* lnk_w  = (const float*)d_in[12];
  const float* lnk_b  = (const float*)d_in[13];
  const float* lnv_w  = (const float*)d_in[14];
  const float* lnv_b  = (const float*)d_in[15];
  const float* in_w   = (const float*)d_in[16];
  const float* in_b   = (const float*)d_in[17];
  const float* out_w  = (const float*)d_in[18];
  const float* out_b  = (const float*)d_in[19];
  const float* mlp_w1 = (const float*)d_in[20];
  const float* mlp_b1 = (const float*)d_in[21];
  const float* mlp_w2 = (const float*)d_in[22];
  const float* mlp_b2 = (const float*)d_in[23];
  float* out = (float*)d_out;

  char* base = (char*)d_ws;
  size_t off = 0;
  auto alloc_us = [&](size_t elems) -> u16* {
    u16* r = (u16*)(base + off);
    off += ((elems * 2 + 255) & ~(size_t)255);
    return r;
  };
  const size_t CC = 1024 * 1024;
  u16* wb_q   = alloc_us(CC);
  u16* wb_kv1 = alloc_us(2 * CC);
  u16* wb_k2  = alloc_us(CC);
  u16* wb_v2  = alloc_us(CC);
  u16* wb_in  = alloc_us(3 * CC);
  u16* wb_out = alloc_us(CC);
  u16* wb_m1  = alloc_us(2 * CC);
  u16* wb_m2  = alloc_us(4 * CC);
  float* b_kv1 = (float*)(base + off); off += 2048 * 4;
  float* b_zero = (float*)(base + off); off += 1024 * 4;

  auto cvt = [&](const float* s, u16* d, size_t n) {
    int n4 = (int)(n / 4);
    cvt_w<<<(n4 + 255) / 256, 256, 0, stream>>>(s, d, n4);
  };
  cvt(q_w, wb_q, CC);
  cvt(k_w1, wb_kv1, CC);        cvt(v_w1, wb_kv1 + CC, CC);
  cvt(k_w2, wb_k2, CC);         cvt(v_w2, wb_v2, CC);
  cvt(in_w, wb_in, 3 * CC);     cvt(out_w, wb_out, CC);
  cvt(mlp_w1, wb_m1, 2 * CC);   cvt(mlp_w2, wb_m2, 4 * CC);
  cat_bias<<<4, 256, 0, stream>>>(k_b1, v_b1, b_kv1, b_zero);

  // Flat token space: 32 dg-planes of 2560 tokens; largest chunk that fits.
  int dgc = 1;
  for (int cand = 32; cand >= 1; cand >>= 1) {
    size_t Tc_ = (size_t)cand * 2560;
    if (off + Tc_ * 11520ull + (1ull << 20) <= ws_size) { dgc = cand; break; }
  }
  const int Tc = dgc * 2560;   // tokens per chunk
  const int Tq = dgc * 320;    // queries per chunk

  u16* Xb  = alloc_us((size_t)Tc * 1024);
  u16* Hb2 = alloc_us((size_t)Tc * 2048);
  u16* Kb  = alloc_us((size_t)Tc * 1024);
  u16* Vb  = alloc_us((size_t)Tc * 1024);
  u16* Qp  = alloc_us((size_t)Tq * 1024);
  u16* QQ  = alloc_us((size_t)Tq * 1024);
  u16* QHb = alloc_us((size_t)Tq * 1024);
  u16* Ob  = alloc_us((size_t)Tq * 1024);
  u16* O2  = alloc_us((size_t)Tq * 1024);
  u16* Hm  = Kb;  // final-MLP hidden reuses Kb (Tq*2048 <= Tc*1024)

  auto launch = [&](int EPI, int N, int K,
                    const u16* A1, const u16* B1, const float* s1, u16* C1,
                    int M1, int lda1,
                    const u16* A2, const u16* B2, const float* s2, u16* C2,
                    int M2, int lda2,
                    const u16* A3, const u16* B3, const float* s3, u16* C3,
                    int M3, int lda3, float* Cf) {
    int nbx = (M1 + M2 + M3) / 128, nby = N / 128;
    dim3 g(nbx * nby);
    if (K == 1024) {
      switch (EPI) {
        case 0: gemm_bt<0, 1024><<<g, 256, 0, stream>>>(A1, B1, s1, Cf, C1, M1, N, lda1, nbx, nby, A2, B2, s2, C2, M2, lda2, A3, B3, s3, C3, M3, lda3); break;
        case 1: gemm_bt<1, 1024><<<g, 256, 0, stream>>>(A1, B1, s1, Cf, C1, M1, N, lda1, nbx, nby, A2, B2, s2, C2, M2, lda2, A3, B3, s3, C3, M3, lda3); break;
        case 2: gemm_bt<2, 1024><<<g, 256, 0, stream>>>(A1, B1, s1, Cf, C1, M1, N, lda1, nbx, nby, A2, B2, s2, C2, M2, lda2, A3, B3, s3, C3, M3, lda3); break;
        default: gemm_bt<3, 1024><<<g, 256, 0, stream>>>(A1, B1, s1, Cf, C1, M1, N, lda1, nbx, nby, A2, B2, s2, C2, M2, lda2, A3, B3, s3, C3, M3, lda3); break;
      }
    } else {
      switch (EPI) {
        case 0: gemm_bt<0, 2048><<<g, 256, 0, stream>>>(A1, B1, s1, Cf, C1, M1, N, lda1, nbx, nby, A2, B2, s2, C2, M2, lda2, A3, B3, s3, C3, M3, lda3); break;
        case 1: gemm_bt<1, 2048><<<g, 256, 0, stream>>>(A1, B1, s1, Cf, C1, M1, N, lda1, nbx, nby, A2, B2, s2, C2, M2, lda2, A3, B3, s3, C3, M3, lda3); break;
        case 2: gemm_bt<2, 2048><<<g, 256, 0, stream>>>(A1, B1, s1, Cf, C1, M1, N, lda1, nbx, nby, A2, B2, s2, C2, M2, lda2, A3, B3, s3, C3, M3, lda3); break;
        default: gemm_bt<3, 2048><<<g, 256, 0, stream>>>(A1, B1, s1, Cf, C1, M1, N, lda1, nbx, nby, A2, B2, s2, C2, M2, lda2, A3, B3, s3, C3, M3, lda3); break;
      }
    }
  };
  const u16* Z = nullptr;

  for (int dg0 = 0; dg0 < 32; dg0 += dgc) {
    const float* xg = x + (size_t)dg0 * 2560 * 1024;
    long q0g = (long)dg0 * 320;

    pool_cvt<<<Tq, 256, 0, stream>>>(xg, Xb, Qp);

    // fused k1+v1 -> gelu -> Hb2 (Tc x 2048)
    launch(1, 2048, 1024, Xb, wb_kv1, b_kv1, Hb2, Tc, 1024,
           Z, Z, nullptr, nullptr, 0, 0, Z, Z, nullptr, nullptr, 0, 0, nullptr);

    // grouped k2 + v2 + q-proj (N=1024, K=1024; per-group lda)
    launch(0, 1024, 1024, Hb2, wb_k2, k_b2, Kb, Tc, 2048,
           Hb2 + 1024, wb_v2, v_b2, Vb, Tc, 2048,
           Qp, wb_q, b_zero, QQ, Tq, 1024, nullptr);

    // fused LN(K) + LN(V) + LN(Q)
    ln3_ip<<<2 * Tc + Tq, 256, 0, stream>>>(Kb, lnk_w, lnk_b, Vb, lnv_w, lnv_b,
                                            QQ, lnq_w, lnq_b, Tc, Tc);

    // grouped kh + vh + qh (all N=1024, K=1024, lda=1024)
    launch(0, 1024, 1024, Kb, wb_in + CC, in_b + 1024, Xb, Tc, 1024,
           Vb, wb_in + 2 * CC, in_b + 2048, Hb2, Tc, 1024,
           QQ, wb_in, in_b, QHb, Tq, 1024, nullptr);

    attn_k<<<Tq, 256, 0, stream>>>(QHb, Xb, Hb2, Ob);

    // out-proj, then final MLP
    launch(0, 1024, 1024, Ob, wb_out, out_b, O2, Tq, 1024,
           Z, Z, nullptr, nullptr, 0, 0, Z, Z, nullptr, nullptr, 0, 0, nullptr);
    launch(1, 2048, 1024, O2, wb_m1, mlp_b1, Hm, Tq, 1024,
           Z, Z, nullptr, nullptr, 0, 0, Z, Z, nullptr, nullptr, 0, 0, nullptr);
    launch(2, 2048, 2048, Hm, wb_m2, mlp_b2, nullptr, Tq, 2048,
           Z, Z, nullptr, nullptr, 0, 0, Z, Z, nullptr, nullptr, 0, 0,
           out + q0g * 2048);
  }
}